// Round 12
// baseline (50.388 us; speedup 1.0000x reference)
//
#include <hip/hip_runtime.h>

typedef __attribute__((ext_vector_type(4))) float f32x4;
typedef __attribute__((ext_vector_type(8))) short bf16x8;

#define NP 4096
#define PB 8               // peds per block
#define GP 520             // grid LDS row pitch (shorts); 1040B rows -> 2-way reads

__device__ __forceinline__ unsigned short f2bf(float f) {
  unsigned int u = __float_as_uint(f);
  u = u + 0x7FFFu + ((u >> 16) & 1u);   // round-to-nearest-even
  return (unsigned short)(u >> 16);
}

// Single fused kernel: 512 blocks x 512 threads, 8 peds/block.
// Phase 1 (pool): lane owns j = jo+tid (loaded ONCE, serves all 8 peds).
// Per in-range pair ONE u64 LDS atomic packing (qx+2^14)<<38 | (qy+2^14)<<12 | 1,
// scale 2^-11 (order-independent integer accumulation; absmax 0.0156 across
// 7 rounds). Binning: fma approx + exact-IEEE-div fallback when any lane in
// the wave is within 1e-4 of a cell boundary -> bit-exact vs numpy.
// Self-pair lands in cell 136 with qx=qy=0, cnt 1; compensated at decode.
// Phase 2: decode acc -> bf16 grid[8][..] in LDS (mean per cell); rows 8..15
// zeroed (M=16 MFMA padding).
// Phase 3: out[8][256] = relu(grid[8x512] @ W^T + b) via 16x16x32 MFMA.
// Wave w owns out cols [32w,32w+32); A from LDS, B = W fp32 streamed from L2,
// converted inline to bf16. No workspace, no second dispatch.
__global__ __launch_bounds__(512) void fused_kernel(
    const float2* __restrict__ pos, const float2* __restrict__ past,
    const float* __restrict__ W, const float* __restrict__ bias,
    float* __restrict__ out) {
  __shared__ unsigned long long acc[PB][256];   // 16 KB
  __shared__ unsigned short grid[16][GP];       // 16.6 KB
  const int tid = threadIdx.x;
  const int ibase = blockIdx.x * PB;

  for (int idx = tid; idx < PB * 256; idx += 512)
    ((unsigned long long*)acc)[idx] = 0ull;
  for (int idx = tid; idx < 16 * GP / 2; idx += 512)
    ((unsigned int*)grid)[idx] = 0u;
  __syncthreads();

  // ---- phase 1: pool ----
  float2 pip[PB];
  float vix[PB], viy[PB];
#pragma unroll
  for (int t = 0; t < PB; ++t) {
    float2 p = pos[ibase + t];
    float2 q = past[ibase + t];
    pip[t] = p;
    vix[t] = p.x - q.x;
    viy[t] = p.y - q.y;
  }
  const float inv06 = 1.0f / 0.6f;

  float2 pj = pos[tid];
  float2 qj = past[tid];
  for (int jo = 0; jo < NP; jo += 512) {
    const float2 cpj = pj;
    const float2 cqj = qj;
    if (jo + 512 < NP) {          // 2-deep pipeline: prefetch next j
      pj = pos[jo + 512 + tid];
      qj = past[jo + 512 + tid];
    }
    const float vjx = cpj.x - cqj.x;
    const float vjy = cpj.y - cqj.y;
#pragma unroll
    for (int t = 0; t < PB; ++t) {
      float rx = cpj.x - pip[t].x;
      float ry = cpj.y - pip[t].y;
      float ax = __builtin_fmaf(rx, inv06, 8.0f);
      float ay = __builtin_fmaf(ry, inv06, 8.0f);
      bool unc = (fabsf(ax - rintf(ax)) < 1e-4f) |
                 (fabsf(ay - rintf(ay)) < 1e-4f);
      float fx, fy;
      if (__any(unc)) {
        // exact IEEE fp32 division path to match numpy floor(rel/0.6 + 8)
        fx = floorf(rx / 0.6f + 8.0f);
        fy = floorf(ry / 0.6f + 8.0f);
      } else {
        fx = floorf(ax);
        fy = floorf(ay);
      }
      int ix = (int)fx;
      int iy = (int)fy;
      if (((unsigned)ix < 16u) & ((unsigned)iy < 16u)) {
        unsigned int qx = (unsigned int)((int)rintf((vjx - vix[t]) * 2048.0f) + 16384);
        unsigned int qy = (unsigned int)((int)rintf((vjy - viy[t]) * 2048.0f) + 16384);
        unsigned long long p = ((unsigned long long)qx << 38) |
                               ((unsigned long long)qy << 12) | 1ull;
        atomicAdd(&acc[t][(ix << 4) + iy], p);
      }
    }
  }
  __syncthreads();

  // ---- phase 2: decode + normalize -> bf16 grid rows 0..7 ----
#pragma unroll
  for (int idx = tid; idx < PB * 256; idx += 512) {
    const int ped = idx >> 8;
    const int cell = idx & 255;
    unsigned long long raw = acc[ped][cell];
    unsigned int cnt = (unsigned int)(raw & 0xFFFull);
    int sxq = (int)((unsigned int)(raw >> 38)) - (int)(cnt << 14);
    int syq = (int)((unsigned int)((raw >> 12) & 0x3FFFFFFull)) - (int)(cnt << 14);
    float cn = (float)cnt - ((cell == 136) ? 1.0f : 0.0f);
    float d = fmaxf(cn, 1.0f);
    float sx = (float)sxq * (1.0f / 2048.0f);
    float sy = (float)syq * (1.0f / 2048.0f);
    unsigned int packed =
        ((unsigned int)f2bf(sy / d) << 16) | (unsigned int)f2bf(sx / d);
    *(unsigned int*)&grid[ped][cell * 2] = packed;
  }
  __syncthreads();

  // ---- phase 3: MFMA gemm: out[8][256] = relu(grid @ W^T + bias) ----
  const int lane = tid & 63;
  const int w = tid >> 6;           // 0..7 -> n-block [32w, 32w+32)
  const int lrow = lane & 15;
  const int lk8 = (lane >> 4) * 8;
  const int nb = w * 32;

  auto ldb = [&](const float* p) {
    float4 w0 = *(const float4*)p;
    float4 w1 = *(const float4*)(p + 4);
    bf16x8 bv;
    bv[0] = (short)f2bf(w0.x); bv[1] = (short)f2bf(w0.y);
    bv[2] = (short)f2bf(w0.z); bv[3] = (short)f2bf(w0.w);
    bv[4] = (short)f2bf(w1.x); bv[5] = (short)f2bf(w1.y);
    bv[6] = (short)f2bf(w1.z); bv[7] = (short)f2bf(w1.w);
    return bv;
  };

  f32x4 o0 = {0.f, 0.f, 0.f, 0.f};
  f32x4 o1 = {0.f, 0.f, 0.f, 0.f};
  const float* Wr0 = &W[(size_t)(nb + lrow) * 512 + lk8];
  const float* Wr1 = &W[(size_t)(nb + 16 + lrow) * 512 + lk8];

  for (int ks = 0; ks < 16; ks += 2) {
    bf16x8 av[2], b0[2], b1[2];
#pragma unroll
    for (int u = 0; u < 2; ++u) {
      const int k0 = (ks + u) * 32;
      av[u] = *(const bf16x8*)&grid[lrow][k0 + lk8];
      b0[u] = ldb(Wr0 + k0);
      b1[u] = ldb(Wr1 + k0);
    }
#pragma unroll
    for (int u = 0; u < 2; ++u) {
      o0 = __builtin_amdgcn_mfma_f32_16x16x32_bf16(av[u], b0[u], o0, 0, 0, 0);
      o1 = __builtin_amdgcn_mfma_f32_16x16x32_bf16(av[u], b1[u], o1, 0, 0, 0);
    }
  }

  // D layout: row(ped) = (lane>>4)*4 + q, col = lane&15; store rows < PB only
  const int rq = (lane >> 4) * 4;
  const float bv0 = bias[nb + lrow];
  const float bv1 = bias[nb + 16 + lrow];
#pragma unroll
  for (int q = 0; q < 4; ++q) {
    const int row = rq + q;
    if (row < PB) {
      const size_t r = (size_t)(ibase + row) * 256;
      out[r + nb + lrow] = fmaxf(o0[q] + bv0, 0.0f);
      out[r + nb + 16 + lrow] = fmaxf(o1[q] + bv1, 0.0f);
    }
  }
}

extern "C" void kernel_launch(void* const* d_in, const int* in_sizes, int n_in,
                              void* d_out, int out_size, void* d_ws, size_t ws_size,
                              hipStream_t stream) {
  // inputs: 0=h (unused), 1=positions, 2=past_positions, 3=W_emb, 4=b_emb
  const float2* pos = (const float2*)d_in[1];
  const float2* past = (const float2*)d_in[2];
  const float* W = (const float*)d_in[3];
  const float* bias = (const float*)d_in[4];
  float* out = (float*)d_out;

  fused_kernel<<<NP / PB, 512, 0, stream>>>(pos, past, W, bias, out);
}

// Round 13
// 34.455 us; speedup vs baseline: 1.4624x; 1.4624x over previous
//
#include <hip/hip_runtime.h>

typedef __attribute__((ext_vector_type(4))) float f32x4;
typedef __attribute__((ext_vector_type(8))) short bf16x8;

#define NP 4096

__device__ __forceinline__ unsigned short f2bf(float f) {
  unsigned int u = __float_as_uint(f);
  u = u + 0x7FFFu + ((u >> 16) & 1u);   // round-to-nearest-even
  return (unsigned short)(u >> 16);
}

// ---------------- pool: lane-owns-j, 4 peds amortized (R11 body) -----------
// XCD-matched mapping: block b (round-robin XCD b%8) owns peds
// (b%8)*512 + (b/8)*4 + {0..3}, so each XCD's L2 holds the gridws rows of a
// contiguous 512-ped slab -- the gemm consumer is mapped to read them locally.
// Per in-range pair: ONE u64 LDS atomic packing (qx+2^14)<<38 | (qy+2^14)<<12 | 1,
// scale 2^-11 (order-independent). Binning: fma approx + exact-IEEE-div
// fallback when any lane within 1e-4 of a cell boundary (bit-exact vs numpy).
// Self-pair lands in cell 136 with qx=qy=0, cnt 1; compensated at decode.
// Threads 0..15 also convert 128 W elements fp32->bf16 (1024 x 128 = 256*512).
__global__ __launch_bounds__(256, 8) void pool_kernel(
    const float2* __restrict__ pos, const float2* __restrict__ past,
    const float* __restrict__ W, unsigned short* __restrict__ Wb,
    unsigned short* __restrict__ gridws) {
  __shared__ unsigned long long acc[4][256];   // 8 KB
  const int tid = threadIdx.x;
  const int b = blockIdx.x;
  const int ibase = (b & 7) * 512 + (b >> 3) * 4;   // XCD-contiguous ped slab

  if (tid < 16) {
    int idx = b * 128 + tid * 8;
    float4 w0 = *(const float4*)&W[idx];
    float4 w1 = *(const float4*)&W[idx + 4];
    bf16x8 bv;
    bv[0] = (short)f2bf(w0.x); bv[1] = (short)f2bf(w0.y);
    bv[2] = (short)f2bf(w0.z); bv[3] = (short)f2bf(w0.w);
    bv[4] = (short)f2bf(w1.x); bv[5] = (short)f2bf(w1.y);
    bv[6] = (short)f2bf(w1.z); bv[7] = (short)f2bf(w1.w);
    *(bf16x8*)&Wb[idx] = bv;
  }

  for (int idx = tid; idx < 1024; idx += 256)
    ((unsigned long long*)acc)[idx] = 0ull;
  __syncthreads();

  float2 pip[4];
  float vix[4], viy[4];
#pragma unroll
  for (int t = 0; t < 4; ++t) {
    float2 p = pos[ibase + t];
    float2 q = past[ibase + t];
    pip[t] = p;
    vix[t] = p.x - q.x;
    viy[t] = p.y - q.y;
  }
  const float inv06 = 1.0f / 0.6f;

  for (int jo = 0; jo < NP; jo += 256) {
    const int j = jo + tid;
    const float2 pj = pos[j];
    const float2 qj = past[j];
    const float vjx = pj.x - qj.x;
    const float vjy = pj.y - qj.y;
#pragma unroll
    for (int t = 0; t < 4; ++t) {
      float rx = pj.x - pip[t].x;
      float ry = pj.y - pip[t].y;
      float ax = __builtin_fmaf(rx, inv06, 8.0f);
      float ay = __builtin_fmaf(ry, inv06, 8.0f);
      bool unc = (fabsf(ax - rintf(ax)) < 1e-4f) |
                 (fabsf(ay - rintf(ay)) < 1e-4f);
      float fx, fy;
      if (__any(unc)) {
        // exact IEEE fp32 division path to match numpy floor(rel/0.6 + 8)
        fx = floorf(rx / 0.6f + 8.0f);
        fy = floorf(ry / 0.6f + 8.0f);
      } else {
        fx = floorf(ax);
        fy = floorf(ay);
      }
      int ix = (int)fx;
      int iy = (int)fy;
      if (((unsigned)ix < 16u) & ((unsigned)iy < 16u)) {
        unsigned int qx = (unsigned int)((int)rintf((vjx - vix[t]) * 2048.0f) + 16384);
        unsigned int qy = (unsigned int)((int)rintf((vjy - viy[t]) * 2048.0f) + 16384);
        unsigned long long p = ((unsigned long long)qx << 38) |
                               ((unsigned long long)qy << 12) | 1ull;
        atomicAdd(&acc[t][(ix << 4) + iy], p);
      }
    }
  }
  __syncthreads();

  // epilogue: decode u64, normalize (mean per cell), store bf16 [NP][512]
  const int cell = tid;  // 0..255
  const float selfc = (cell == 136) ? 1.0f : 0.0f;
#pragma unroll
  for (int t = 0; t < 4; ++t) {
    unsigned long long raw = acc[t][cell];
    unsigned int cnt = (unsigned int)(raw & 0xFFFull);
    int sxq = (int)((unsigned int)(raw >> 38)) - (int)(cnt << 14);
    int syq = (int)((unsigned int)((raw >> 12) & 0x3FFFFFFull)) - (int)(cnt << 14);
    float cn = (float)cnt - selfc;
    float d = fmaxf(cn, 1.0f);
    float sx = (float)sxq * (1.0f / 2048.0f);
    float sy = (float)syq * (1.0f / 2048.0f);
    unsigned int packed =
        ((unsigned int)f2bf(sy / d) << 16) | (unsigned int)f2bf(sx / d);
    *(unsigned int*)&gridws[(size_t)(ibase + t) * 512 + cell * 2] = packed;
  }
}

// ---------------- GEMM: split-K (R11 body), XCD-matched consumer -----------
// C[4096][256] = relu(A[4096][512](bf16) @ Wb[256][512]^T + b), fp32 out.
// 1-D grid, 1024 blocks: block g -> xcd=g%8, idx=g/8; m-tile = xcd*32+(idx&31)
// (peds xcd*512 + ...), n-tile = idx>>5. Every A-row this block reads was
// written by a pool block on the SAME XCD -> local-L2 hits, no cross-XCD path.
// Block = 16x64 out tile, 4 waves; wave w owns K-slice [128w,128w+128) = 4
// MFMA k-steps (2-deep loads, no k-barriers). Partials red[4][64][20], one
// barrier, float4 reduce + bias + relu + coalesced stores.
__global__ __launch_bounds__(256) void gemm_kernel(
    const unsigned short* __restrict__ A, const unsigned short* __restrict__ Wb,
    const float* __restrict__ bias, float* __restrict__ out) {
  __shared__ float red[4][64][20];
  const int tid = threadIdx.x;
  const int lane = tid & 63;
  const int w = tid >> 6;            // 0..3 K-slice
  const int g = blockIdx.x;
  const int xcd = g & 7;
  const int idx = g >> 3;
  const int mbase = (xcd * 32 + (idx & 31)) * 16;
  const int nbase = (idx >> 5) * 64;
  const int lrow = lane & 15;
  const int lk8 = (lane >> 4) * 8;

  f32x4 acc[4] = {};
#pragma unroll
  for (int ksp = 0; ksp < 4; ksp += 2) {
    bf16x8 a[2], b[2][4];
#pragma unroll
    for (int u = 0; u < 2; ++u) {
      const int k0 = w * 128 + (ksp + u) * 32 + lk8;
      a[u] = *(const bf16x8*)&A[(size_t)(mbase + lrow) * 512 + k0];
#pragma unroll
      for (int nf = 0; nf < 4; ++nf)
        b[u][nf] = *(const bf16x8*)&Wb[(size_t)(nbase + nf * 16 + lrow) * 512 + k0];
    }
#pragma unroll
    for (int u = 0; u < 2; ++u)
#pragma unroll
      for (int nf = 0; nf < 4; ++nf)
        acc[nf] = __builtin_amdgcn_mfma_f32_16x16x32_bf16(
            a[u], b[u][nf], acc[nf], 0, 0, 0);
  }

  // D layout: row(m) = (lane>>4)*4 + q, col(n) = nf*16 + (lane&15)
  const int rq = (lane >> 4) * 4;
#pragma unroll
  for (int nf = 0; nf < 4; ++nf)
    *(f32x4*)&red[w][nf * 16 + lrow][rq] = acc[nf];
  __syncthreads();

  const int col = tid & 63;
  const int mq = (tid >> 6) * 4;
  f32x4 s = {};
#pragma unroll
  for (int w2 = 0; w2 < 4; ++w2) {
    f32x4 r = *(const f32x4*)&red[w2][col][mq];
    s += r;
  }
  const float bv = bias[nbase + col];
#pragma unroll
  for (int q = 0; q < 4; ++q)
    out[(size_t)(mbase + mq + q) * 256 + nbase + col] = fmaxf(s[q] + bv, 0.0f);
}

extern "C" void kernel_launch(void* const* d_in, const int* in_sizes, int n_in,
                              void* d_out, int out_size, void* d_ws, size_t ws_size,
                              hipStream_t stream) {
  // inputs: 0=h (unused), 1=positions, 2=past_positions, 3=W_emb, 4=b_emb
  const float2* pos = (const float2*)d_in[1];
  const float2* past = (const float2*)d_in[2];
  const float* W = (const float*)d_in[3];
  const float* bias = (const float*)d_in[4];
  float* out = (float*)d_out;

  unsigned short* gridws = (unsigned short*)d_ws;                         // 4 MB
  unsigned short* Wb = (unsigned short*)((char*)d_ws + 4 * 1024 * 1024);  // 256 KB

  pool_kernel<<<NP / 4, 256, 0, stream>>>(pos, past, W, Wb, gridws);
  gemm_kernel<<<1024, 256, 0, stream>>>(gridws, Wb, bias, out);
}